// Round 11
// baseline (337.896 us; speedup 1.0000x reference)
//
#include <hip/hip_runtime.h>
#include <hip/hip_bf16.h>
#include <math.h>

typedef __attribute__((ext_vector_type(8))) __bf16 bf16x8;
typedef __attribute__((ext_vector_type(4))) __bf16 bf16x4;
typedef __attribute__((ext_vector_type(4))) float f32x4;

#define B_ 4
#define N_ 2048
#define D_ 512
#define H_ 8
#define DK_ 64
#define F_ 2048

__device__ __forceinline__ void async16(const __bf16* g, __bf16* l) {
  __builtin_amdgcn_global_load_lds((const __attribute__((address_space(1))) void*)g,
                                   (__attribute__((address_space(3))) void*)l, 16, 0, 0);
}

// ---------------- merged prologue: weight prep + bitmask + LN1 + rope cos/sin table ----------------
// blocks [0,774): weight transposes + bias concat
// blocks [774,8966): mask -> u64 bitmask, 8 grid-stride passes
// blocks [8966,11014): LN1 (x -> xn bf16)
// blocks [11014,12038): ctab[row][d] = (cos,sin)(pos[row] * 10000^(-d/32)), d in 0..31
//   (2MB table; QKV-gemm epilogue applies RoPE in-register -> no qkv Q/K roundtrip)
__global__ __launch_bounds__(256) void prep_bm_ln(const float* __restrict__ wq,
                                                  const float* __restrict__ wk,
                                                  const float* __restrict__ wv,
                                                  const float* __restrict__ wo,
                                                  const float* __restrict__ w1,
                                                  const float* __restrict__ w2,
                                                  const float* __restrict__ bq,
                                                  const float* __restrict__ bk,
                                                  const float* __restrict__ bv,
                                                  __bf16* __restrict__ wqkvt,
                                                  __bf16* __restrict__ wot,
                                                  __bf16* __restrict__ w1t,
                                                  __bf16* __restrict__ w2t,
                                                  float* __restrict__ bqkv,
                                                  const int* __restrict__ mask,
                                                  unsigned long long* __restrict__ bm,
                                                  const float* __restrict__ x,
                                                  const float* __restrict__ g,
                                                  const float* __restrict__ bb_,
                                                  __bf16* __restrict__ xnout,
                                                  const int* __restrict__ pos,
                                                  float2* __restrict__ ctab) {
  __shared__ float t[64][65];
  const int id = blockIdx.x;
  if (id < 774) {
    if (id >= 768) {  // bias concat (6 blocks)
      int i = (id - 768) * 256 + threadIdx.x;
      bqkv[i] = (i < 512) ? bq[i] : (i < 1024) ? bk[i - 512] : bv[i - 1024];
      return;
    }
    const float* in;
    __bf16* outp;
    int k0, n0, K, Nc;
    if (id < 256) {
      const float* src[4] = {wq, wk, wv, wo};
      __bf16* dst[4] = {wqkvt, wqkvt + 512 * 512, wqkvt + 1024 * 512, wot};
      int w = id >> 6, tl = id & 63;
      in = src[w]; outp = dst[w]; k0 = (tl & 7) * 64; n0 = (tl >> 3) * 64; K = 512; Nc = 512;
    } else if (id < 512) {
      int tl = id - 256;
      in = w1; outp = w1t; k0 = (tl & 7) * 64; n0 = (tl >> 3) * 64; K = 512; Nc = 2048;
    } else {
      int tl = id - 512;
      in = w2; outp = w2t; k0 = (tl & 31) * 64; n0 = (tl >> 5) * 64; K = 2048; Nc = 512;
    }
    const int c = threadIdx.x & 63, r4 = threadIdx.x >> 6;
#pragma unroll
    for (int p = 0; p < 16; p++) {
      int rr = p * 4 + r4;
      t[rr][c] = in[(size_t)(k0 + rr) * Nc + n0 + c];
    }
    __syncthreads();
#pragma unroll
    for (int p = 0; p < 16; p++) {
      int rr = p * 4 + r4;
      outp[(size_t)(n0 + rr) * K + k0 + c] = (__bf16)t[c][rr];
    }
  } else if (id < 774 + 8192) {
    const int bb = id - 774;
#pragma unroll
    for (int it = 0; it < 8; it++) {
      size_t tt = ((size_t)(it * 8192 + bb)) * 256 + threadIdx.x;
      int m = mask[tt];
      unsigned long long w = __ballot(m != 0);
      if ((threadIdx.x & 63) == 0) bm[tt >> 6] = w;
    }
  } else if (id < 11014) {
    int row = (id - 8966) * 4 + (threadIdx.x >> 6);
    int lane = threadIdx.x & 63;
    const float* xr = x + (size_t)row * D_ + lane * 8;
    float4 a0 = *(const float4*)xr;
    float4 a1 = *(const float4*)(xr + 4);
    float v[8] = {a0.x, a0.y, a0.z, a0.w, a1.x, a1.y, a1.z, a1.w};
    float s = 0.f;
#pragma unroll
    for (int i = 0; i < 8; i++) s += v[i];
#pragma unroll
    for (int off = 1; off < 64; off <<= 1) s += __shfl_xor(s, off);
    float mu = s * (1.f / D_);
    float q = 0.f;
#pragma unroll
    for (int i = 0; i < 8; i++) { float d = v[i] - mu; q += d * d; }
#pragma unroll
    for (int off = 1; off < 64; off <<= 1) q += __shfl_xor(q, off);
    float rs = rsqrtf(q * (1.f / D_) + 1e-5f);
    const float* gp = g + lane * 8;
    const float* bp = bb_ + lane * 8;
    alignas(16) __bf16 o[8];
#pragma unroll
    for (int i = 0; i < 8; i++) o[i] = (__bf16)((v[i] - mu) * rs * gp[i] + bp[i]);
    *(bf16x8*)(xnout + (size_t)row * D_ + lane * 8) = *(bf16x8*)o;
  } else {  // cos/sin table: e = row*32 + d
    int e = (id - 11014) * 256 + threadIdx.x;
    int row = e >> 5, d = e & 31;
    float p = (float)pos[row];
    float inv = __expf(-(float)d * (9.210340371976184f / 32.f));  // 10000^(-d/32)
    float sn, cs;
    sincosf(p * inv, &sn, &cs);
    ctab[e] = make_float2(cs, sn);
  }
}

// ---------------- layernorm: one wave per row of 512, fp32 in -> bf16 out (LN2) ----------------
__global__ __launch_bounds__(256) void ln_fwd(const float* __restrict__ x,
                                              const float* __restrict__ g,
                                              const float* __restrict__ b,
                                              __bf16* __restrict__ out) {
  int row = blockIdx.x * 4 + (threadIdx.x >> 6);
  int lane = threadIdx.x & 63;
  const float* xr = x + (size_t)row * D_ + lane * 8;
  float4 a0 = *(const float4*)xr;
  float4 a1 = *(const float4*)(xr + 4);
  float v[8] = {a0.x, a0.y, a0.z, a0.w, a1.x, a1.y, a1.z, a1.w};
  float s = 0.f;
#pragma unroll
  for (int i = 0; i < 8; i++) s += v[i];
#pragma unroll
  for (int off = 1; off < 64; off <<= 1) s += __shfl_xor(s, off);
  float mu = s * (1.f / D_);
  float q = 0.f;
#pragma unroll
  for (int i = 0; i < 8; i++) { float d = v[i] - mu; q += d * d; }
#pragma unroll
  for (int off = 1; off < 64; off <<= 1) q += __shfl_xor(q, off);
  float rs = rsqrtf(q * (1.f / D_) + 1e-5f);
  const float* gp = g + lane * 8;
  const float* bp = b + lane * 8;
  alignas(16) __bf16 o[8];
#pragma unroll
  for (int i = 0; i < 8; i++) o[i] = (__bf16)((v[i] - mu) * rs * gp[i] + bp[i]);
  *(bf16x8*)(out + (size_t)row * D_ + lane * 8) = *(bf16x8*)o;
}

// ---------------- V transpose only (rope for Q/K now fused into QKV-gemm epilogue) ----------------
__global__ __launch_bounds__(256) void vtrans(const __bf16* __restrict__ qkv,
                                              __bf16* __restrict__ vt) {
  __shared__ __bf16 tl[64][65];
  const int lin = blockIdx.x;
  const int n0 = (lin & 31) * 64, h = (lin >> 5) & 7, b = lin >> 8;
  const int c = threadIdx.x & 63, rr = threadIdx.x >> 6;
#pragma unroll
  for (int p = 0; p < 16; p++) {
    int i = p * 4 + rr;
    tl[i][c] = qkv[(size_t)(b * N_ + n0 + i) * 1536 + 1024 + h * 64 + c];
  }
  __syncthreads();
  size_t ob = (size_t)(b * H_ + h) * DK_ * N_;
#pragma unroll
  for (int p = 0; p < 16; p++) {
    int dd = p * 4 + rr;
    vt[ob + (size_t)dd * N_ + n0 + c] = tl[c][dd];
  }
}

// XCD-aware block remap for GEMMs (T1; R10: -11us wall). Requires nwg % 8 == 0.
__device__ __forceinline__ int xcd_remap(int bid, int nwg) {
  return (bid & 7) * (nwg >> 3) + (bid >> 3);
}

// ---------------- QKV GEMM with fused RoPE epilogue ----------------
// R11: rope pairs (d, d+32) map to acc[mi][ni] and acc[mi][ni^2] in the SAME thread
// (cols within a 64-wide wn-block; +32 cols = +2 ni). Apply rope in-register on the
// f32 accumulator (one FEWER bf16 rounding than the old qkv->rope path), write qr/kr
// directly. Kills the 33.6MB qkv Q/K write+reread roundtrip + 8/9 of the rope kernel.
// Q folds 0.125*log2e (attn uses raw v_exp_f32 downstream). V region unchanged ->
// qkv V-slice, transposed by the slim vtrans kernel.
__global__ __launch_bounds__(256) void gemm_qkv(const __bf16* __restrict__ A,
                                                const __bf16* __restrict__ Bt,
                                                const float* __restrict__ bias,
                                                __bf16* __restrict__ qkvV,
                                                __bf16* __restrict__ qr,
                                                __bf16* __restrict__ kr,
                                                const float2* __restrict__ ctab) {
  constexpr int K = 512;
  __shared__ __bf16 As[2][128 * 32];
  __shared__ __bf16 Bs[2][128 * 32];
  const int tid = threadIdx.x;
  const int lane = tid & 63;
  const int wave = tid >> 6;
  const int quad = lane >> 4;
  const int l16 = lane & 15;
  const int gl = xcd_remap(blockIdx.y * 12 + blockIdx.x, 768);
  const int m0 = (gl / 12) * 128;
  const int n0 = (gl % 12) * 128;
  const int wm = (wave >> 1) * 64;
  const int wn = (wave & 1) * 64;
  f32x4 acc[4][4] = {};

  const int c0 = tid, c1 = tid + 256;
  const int ar0 = c0 >> 2, ak0 = (c0 & 3) * 8;
  const int ar1 = c1 >> 2, ak1 = (c1 & 3) * 8;

  auto stage = [&](int k0, int buf) {
    async16(A + (size_t)(m0 + ar0) * K + k0 + ak0, As[buf] + c0 * 8);
    async16(A + (size_t)(m0 + ar1) * K + k0 + ak1, As[buf] + c1 * 8);
    async16(Bt + (size_t)(n0 + ar0) * K + k0 + ak0, Bs[buf] + c0 * 8);
    async16(Bt + (size_t)(n0 + ar1) * K + k0 + ak1, Bs[buf] + c1 * 8);
  };

  stage(0, 0);
  __syncthreads();
  const int niter = K >> 5;
  for (int it = 0; it < niter; it++) {
    const int buf = it & 1;
    if (it + 1 < niter) stage((it + 1) * 32, buf ^ 1);
    bf16x8 af[4], bf[4];
#pragma unroll
    for (int mi = 0; mi < 4; mi++)
      af[mi] = *(const bf16x8*)(As[buf] + (wm + mi * 16 + l16) * 32 + quad * 8);
#pragma unroll
    for (int ni = 0; ni < 4; ni++)
      bf[ni] = *(const bf16x8*)(Bs[buf] + (wn + ni * 16 + l16) * 32 + quad * 8);
#pragma unroll
    for (int mi = 0; mi < 4; mi++)
#pragma unroll
      for (int ni = 0; ni < 4; ni++)
        acc[mi][ni] = __builtin_amdgcn_mfma_f32_16x16x32_bf16(af[mi], bf[ni], acc[mi][ni], 0, 0, 0);
    __syncthreads();  // drains stage(it+1); guards buf reuse
  }

  if (n0 >= 1024) {
    // V region: plain bf16 write into qkv V-slice (row stride 1536)
#pragma unroll
    for (int ni = 0; ni < 4; ni++) {
      const int col = n0 + wn + ni * 16 + l16;
      const float bv = bias[col];
#pragma unroll
      for (int mi = 0; mi < 4; mi++)
#pragma unroll
        for (int r = 0; r < 4; r++) {
          const int row = m0 + wm + mi * 16 + quad * 4 + r;
          qkvV[(size_t)row * 1536 + col] = (__bf16)(acc[mi][ni][r] + bv);
        }
    }
  } else {
    // Q or K region: fused rope. Pairs: (ni=0,ni=2) -> d=l16; (ni=1,ni=3) -> d=16+l16.
    __bf16* outp = (n0 >= 512) ? kr : qr;
    const float sc = (n0 >= 512) ? 1.0f : 0.18033688011112042f;  // Q: 0.125*log2(e)
    const int cl0 = n0 + wn + l16;
    const float bl0 = bias[cl0],      bh0 = bias[cl0 + 32];
    const float bl1 = bias[cl0 + 16], bh1 = bias[cl0 + 48];
    const int h0 = (cl0 >> 6) & 7;   // same head for all 4 cols (d<32, d+32 in same 64-block)
    const int d0 = l16;
#pragma unroll
    for (int mi = 0; mi < 4; mi++)
#pragma unroll
      for (int r = 0; r < 4; r++) {
        const int row = m0 + wm + mi * 16 + quad * 4 + r;
        const int bb2 = row >> 11, nn = row & 2047;
        const size_t ob = ((size_t)(bb2 * 8 + h0) * 2048 + nn) * 64;
        const float2 ct0 = ctab[row * 32 + d0];
        const float2 ct1 = ctab[row * 32 + d0 + 16];
        const float vlo0 = acc[mi][0][r] + bl0, vhi0 = acc[mi][2][r] + bh0;
        const float vlo1 = acc[mi][1][r] + bl1, vhi1 = acc[mi][3][r] + bh1;
        outp[ob + d0]      = (__bf16)((vlo0 * ct0.x - vhi0 * ct0.y) * sc);
        outp[ob + d0 + 32] = (__bf16)((vhi0 * ct0.x + vlo0 * ct0.y) * sc);
        outp[ob + d0 + 16] = (__bf16)((vlo1 * ct1.x - vhi1 * ct1.y) * sc);
        outp[ob + d0 + 48] = (__bf16)((vhi1 * ct1.x + vlo1 * ct1.y) * sc);
      }
  }
}

// ---------------- GEMM 128x128, DOUBLE-BUFFERED K-loop (+ XCD swizzle) ----------------
// R7 lesson: 3-buffer counted-vmcnt regressed here (LDS 48KB dropped FFN1 4->3
// blocks/CU; TLP at 3-4 blocks/CU already hides the drain). Keep 2-buffer.
template <int RELU, int OBF, int RES>
__global__ __launch_bounds__(256) void gemm_bt(const __bf16* __restrict__ A,
                                               const __bf16* __restrict__ Bt,
                                               const float* __restrict__ bias,
                                               const float* __restrict__ res,
                                               void* __restrict__ Cout,
                                               int M, int N, int K) {
  __shared__ __bf16 As[2][128 * 32];
  __shared__ __bf16 Bs[2][128 * 32];
  const int tid = threadIdx.x;
  const int lane = tid & 63;
  const int wave = tid >> 6;
  const int quad = lane >> 4;
  const int l16 = lane & 15;
  const int nwgx = gridDim.x;
  const int gl = xcd_remap(blockIdx.y * nwgx + blockIdx.x, nwgx * gridDim.y);
  const int m0 = (gl / nwgx) * 128;
  const int n0 = (gl % nwgx) * 128;
  const int wm = (wave >> 1) * 64;
  const int wn = (wave & 1) * 64;
  f32x4 acc[4][4] = {};

  const int c0 = tid, c1 = tid + 256;
  const int ar0 = c0 >> 2, ak0 = (c0 & 3) * 8;
  const int ar1 = c1 >> 2, ak1 = (c1 & 3) * 8;

  auto stage = [&](int k0, int buf) {
    async16(A + (size_t)(m0 + ar0) * K + k0 + ak0, As[buf] + c0 * 8);
    async16(A + (size_t)(m0 + ar1) * K + k0 + ak1, As[buf] + c1 * 8);
    async16(Bt + (size_t)(n0 + ar0) * K + k0 + ak0, Bs[buf] + c0 * 8);
    async16(Bt + (size_t)(n0 + ar1) * K + k0 + ak1, Bs[buf] + c1 * 8);
  };

  stage(0, 0);
  __syncthreads();
  const int niter = K >> 5;
  for (int it = 0; it < niter; it++) {
    const int buf = it & 1;
    if (it + 1 < niter) stage((it + 1) * 32, buf ^ 1);
    bf16x8 af[4], bf[4];
#pragma unroll
    for (int mi = 0; mi < 4; mi++)
      af[mi] = *(const bf16x8*)(As[buf] + (wm + mi * 16 + l16) * 32 + quad * 8);
#pragma unroll
    for (int ni = 0; ni < 4; ni++)
      bf[ni] = *(const bf16x8*)(Bs[buf] + (wn + ni * 16 + l16) * 32 + quad * 8);
#pragma unroll
    for (int mi = 0; mi < 4; mi++)
#pragma unroll
      for (int ni = 0; ni < 4; ni++)
        acc[mi][ni] = __builtin_amdgcn_mfma_f32_16x16x32_bf16(af[mi], bf[ni], acc[mi][ni], 0, 0, 0);
    __syncthreads();  // drains stage(it+1); guards buf reuse
  }
#pragma unroll
  for (int ni = 0; ni < 4; ni++) {
    const int col = n0 + wn + ni * 16 + l16;
    const float bv = bias[col];
#pragma unroll
    for (int mi = 0; mi < 4; mi++) {
#pragma unroll
      for (int r = 0; r < 4; r++) {
        const int row = m0 + wm + mi * 16 + quad * 4 + r;
        float v = acc[mi][ni][r] + bv;
        if (RES) v += res[(size_t)row * N + col];
        if (RELU) v = fmaxf(v, 0.f);
        if (OBF) ((__bf16*)Cout)[(size_t)row * N + col] = (__bf16)v;
        else     ((float*)Cout)[(size_t)row * N + col] = v;
      }
    }
  }
}

// ---------------- GEMM 128x64, DOUBLE-BUFFERED K-loop (R8 body + XCD swizzle) ----------------
// R9 lesson: 8-wave/512-thr variant was neutral -- gemm_bt64 is not wave-starved.
template <int RELU, int OBF, int RES>
__global__ __launch_bounds__(256) void gemm_bt64(const __bf16* __restrict__ A,
                                                 const __bf16* __restrict__ Bt,
                                                 const float* __restrict__ bias,
                                                 const float* __restrict__ res,
                                                 void* __restrict__ Cout,
                                                 int M, int N, int K) {
  __shared__ __bf16 As[2][128 * 32];
  __shared__ __bf16 Bs[2][64 * 32];
  const int tid = threadIdx.x;
  const int lane = tid & 63;
  const int wave = tid >> 6;
  const int quad = lane >> 4;
  const int l16 = lane & 15;
  const int nwgx = gridDim.x;
  const int gl = xcd_remap(blockIdx.y * nwgx + blockIdx.x, nwgx * gridDim.y);
  const int m0 = (gl / nwgx) * 128;
  const int n0 = (gl % nwgx) * 64;
  const int wm = wave * 32;
  f32x4 acc[2][4] = {};

  const int ar0 = tid >> 2, ak0 = (tid & 3) * 8;

  auto stage = [&](int k0, int buf) {
    async16(A + (size_t)(m0 + ar0) * K + k0 + ak0, As[buf] + tid * 8);
    async16(A + (size_t)(m0 + 64 + ar0) * K + k0 + ak0, As[buf] + (tid + 256) * 8);
    async16(Bt + (size_t)(n0 + ar0) * K + k0 + ak0, Bs[buf] + tid * 8);
  };

  stage(0, 0);
  __syncthreads();
  const int niter = K >> 5;
  for (int it = 0; it < niter; it++) {
    const int buf = it & 1;
    if (it + 1 < niter) stage((it + 1) * 32, buf ^ 1);
    bf16x8 af[2], bf[4];
#pragma unroll
    for (int mi = 0; mi < 2; mi++)
      af[mi] = *(const bf16x8*)(As[buf] + (wm + mi * 16 + l16) * 32 + quad * 8);
#pragma unroll
    for (int ni = 0; ni < 4; ni++)
      bf[ni] = *(const bf16x8*)(Bs[buf] + (ni * 16 + l16) * 32 + quad * 8);
#pragma unroll
    for (int mi = 0; mi < 2; mi++)
#pragma unroll
      for (int ni = 0; ni < 4; ni++)
        acc[mi][ni] = __builtin_amdgcn_mfma_f32_16x16x32_bf16(af[mi], bf[ni], acc[mi][ni], 0, 0, 0);
    __syncthreads();  // drains stage(it+1); guards buf reuse
  }
#pragma unroll
  for (int ni = 0; ni < 4; ni++) {
    const int col = n0 + ni * 16 + l16;
    const float bv = bias[col];
#pragma unroll
    for (int mi = 0; mi < 2; mi++) {
#pragma unroll
      for (int r = 0; r < 4; r++) {
        const int row = m0 + wm + mi * 16 + quad * 4 + r;
        float v = acc[mi][ni][r] + bv;
        if (RES) v += res[(size_t)row * N + col];
        if (RELU) v = fmaxf(v, 0.f);
        if (OBF) ((__bf16*)Cout)[(size_t)row * N + col] = (__bf16)v;
        else     ((float*)Cout)[(size_t)row * N + col] = v;
      }
    }
  }
}

// ---------------- flash attention: 3-buffer counted-vmcnt pipeline (R8 body, ~64us) ----------------
// Pinned at ~64us by serial-chain latency (VALU cuts land in stall shadow -- R2/R8).
// Invariants: stage->consume distance >= 2 bodies (R6); counted vmcnt(3) not drain-0
// (R5, +8.5%); XCD swizzle (R4, FETCH 70.7->14.4MB); raw v_exp + rope prescale (R8).
__global__ __launch_bounds__(512, 4) void flash_attn(const __bf16* __restrict__ q,
                                                     const __bf16* __restrict__ k,
                                                     const __bf16* __restrict__ vt,
                                                     const unsigned long long* __restrict__ bm,
                                                     __bf16* __restrict__ out) {
  const int bid = blockIdx.x;
  const int gl = ((bid & 7) << 6) | (bid >> 3);  // bijective: 512 = 8*64
  const int qt = gl & 15;
  const int h = (gl >> 4) & 7;
  const int b = gl >> 7;
  const int tid = threadIdx.x;
  const int lane = tid & 63, wave = tid >> 6;   // wave 0..7
  const int quad = lane >> 4, l16 = lane & 15;
  __shared__ __bf16 Ks[3][64 * 64];
  __shared__ __bf16 Vs[3][64 * 64];
  __shared__ __bf16 P[8][16 * 68];  // [wave][qrow x keys(stride 68)]
  const size_t bh = (size_t)b * H_ + h;
  const __bf16* qp = q + (bh * N_ + qt * 128 + wave * 16) * DK_;
  bf16x8 qf[2];
#pragma unroll
  for (int ks = 0; ks < 2; ks++)
    qf[ks] = *(const bf16x8*)(qp + l16 * DK_ + ks * 32 + quad * 8);  // pre-scaled at gemm epilogue
  const __bf16* kbase = k + bh * N_ * DK_;
  const __bf16* vbase = vt + bh * DK_ * N_;
  const int qrow0 = qt * 128 + wave * 16 + l16;
  const unsigned long long* bmr = bm + (size_t)(b * N_ + qrow0) * (N_ / 64);
  const int xo = l16 & 7;  // read-side XOR (== row&7 for all fragment rows)

  f32x4 oacc[4] = {};
  float lsum = 0.f;

  const int sr = tid >> 3;
  const int sj = (tid & 7) ^ (sr & 7);
  const __bf16* ksrc = kbase + sr * DK_ + sj * 8;
  const __bf16* vsrc = vbase + (size_t)sr * N_ + sj * 8;

  auto stage = [&](int kt, int buf) {
    async16(ksrc + (size_t)kt * 64 * DK_, Ks[buf] + tid * 8);
    async16(vsrc + kt * 64, Vs[buf] + tid * 8);
  };

  // prologue: stage tiles 0 and 1; wait only for tile 0 (tile 1 + mask stay in flight)
  stage(0, 0);
  stage(1, 1);
  unsigned long long mw = bmr[0];
  asm volatile("s_waitcnt vmcnt(3)" ::: "memory");
  __builtin_amdgcn_s_barrier();
  __builtin_amdgcn_sched_barrier(0);

  for (int kt = 0; kt < 32; kt++) {
    const int buf = kt % 3;
    // uniform vmem cluster: 2 stage loads + 1 mask load per iteration (dummy at tail)
    const int nstage = (kt + 2 < 32) ? kt + 2 : 31;
    stage(nstage, (kt + 2) % 3);
    const int nmask = (kt + 1 < 32) ? kt + 1 : 31;
    const unsigned long long mw_nxt = bmr[nmask];

    const unsigned long long mws = mw >> (quad * 4);
    // S^T tile: A-operand = K fragment, B-operand = Q fragment (col = qrow)
#pragma unroll
    for (int ci = 0; ci < 4; ci++) {
      const int row = ci * 16 + l16;
      bf16x8 kf0 = *(const bf16x8*)(Ks[buf] + (row * 8 + (quad ^ xo)) * 8);
      bf16x8 kf1 = *(const bf16x8*)(Ks[buf] + (row * 8 + ((4 + quad) ^ xo)) * 8);
      f32x4 a = {0.f, 0.f, 0.f, 0.f};
      a = __builtin_amdgcn_mfma_f32_16x16x32_bf16(kf0, qf[0], a, 0, 0, 0);
      a = __builtin_amdgcn_mfma_f32_16x16x32_bf16(kf1, qf[1], a, 0, 0, 0);
      const unsigned int nib = (unsigned int)(mws >> (ci * 16)) & 15u;
      bf16x4 pk;
#pragma unroll
      for (int r4 = 0; r4 < 4; r4++) {
        float in = ((nib >> r4) & 1u) ? a[r4] : -1e30f;
        float p;
        asm("v_exp_f32 %0, %1" : "=v"(p) : "v"(in));  // 2^in; S pre-scaled by log2e
        lsum += p;
        pk[r4] = (__bf16)p;
      }
      *(bf16x4*)(&P[wave][0] + l16 * 68 + ci * 16 + quad * 4) = pk;
    }
    // P^T fragments (B-operand): row l16 = qrow, keys quad*8+j (same-wave write->read)
    bf16x8 pf0 = *(const bf16x8*)(&P[wave][0] + l16 * 68 + quad * 8);
    bf16x8 pf1 = *(const bf16x8*)(&P[wave][0] + l16 * 68 + 32 + quad * 8);
    // out^T += V^T . P^T
#pragma unroll
    for (int ni = 0; ni < 4; ni++) {
      const int row = ni * 16 + l16;
      bf16x8 vf0 = *(const bf16x8*)(Vs[buf] + (row * 8 + (quad ^ xo)) * 8);
      bf16x8 vf1 = *(const bf16x8*)(Vs[buf] + (row * 8 + ((4 + quad) ^ xo)) * 8);
      oacc[ni] = __builtin_amdgcn_mfma_f32_16x16x32_bf16(vf0, pf0, oacc[ni], 0, 0, 0);
      oacc[ni] = __builtin_amdgcn_mfma_f32_16x16x32_bf16(vf1, pf1, oacc[ni], 0, 0, 0);
    }
    // counted wait: previous stage (issued last iter) retired; this iter's
    // 2 stage loads + 1 mask load may remain in flight across the barrier.
    asm volatile("s_waitcnt vmcnt(3)" ::: "memory");
    __builtin_amdgcn_s_barrier();
    __builtin_amdgcn_sched_barrier(0);
    mw = mw_nxt;
  }
  // row-sum: combine the 4 quads; then store out^T (col l16 = qrow) as 8B packed
  lsum += __shfl_xor(lsum, 16);
  lsum += __shfl_xor(lsum, 32);
  const float inv_l = (lsum > 0.f) ? 1.f / lsum : 0.f;
#pragma unroll
  for (int ni = 0; ni < 4; ni++) {
    bf16x4 ov;
#pragma unroll
    for (int r = 0; r < 4; r++) ov[r] = (__bf16)(oacc[ni][r] * inv_l);
    *(bf16x4*)(out + ((size_t)b * N_ + qrow0) * D_ + h * DK_ + ni * 16 + quad * 4) = ov;
  }
}

// ---------------- workspace layout (bytes) ----------------
static constexpr size_t OFF_XN  = 0;                         // 8,388,608 (xn; reused as LN2 out)
static constexpr size_t OFF_WT  = 8388608;                   // 1,572,864
static constexpr size_t OFF_WO  = OFF_WT + 1572864;          // 524,288
static constexpr size_t OFF_W1  = OFF_WO + 524288;           // 2,097,152
static constexpr size_t OFF_W2  = OFF_W1 + 2097152;          // 2,097,152
static constexpr size_t OFF_BQ  = OFF_W2 + 2097152;          // 6,144
static constexpr size_t OFF_QKV = OFF_BQ + 6144;             // 25,165,824 (h2 overlay)
static constexpr size_t OFF_QR  = OFF_QKV + 25165824;        // 8,388,608
static constexpr size_t OFF_KR  = OFF_QR + 8388608;          // 8,388,608
static constexpr size_t OFF_VT  = OFF_KR + 8388608;          // 8,388,608
static constexpr size_t OFF_AO  = OFF_VT + 8388608;          // 8,388,608
static constexpr size_t OFF_Y   = OFF_AO + 8388608;          // 16,777,216 fp32 y
// overlays in the y region (both dead before o-proj writes y):
//   bm   at OFF_Y            (2MB, used through attn)
//   ctab at OFF_Y + 2MB      (2MB, used through QKV gemm)
// total = 90,183,680 bytes

extern "C" void kernel_launch(void* const* d_in, const int* in_sizes, int n_in,
                              void* d_out, int out_size, void* d_ws, size_t ws_size,
                              hipStream_t stream) {
  const float* x    = (const float*)d_in[0];
  const int*   mask = (const int*)d_in[1];
  const int*   pos  = (const int*)d_in[2];
  const float* wq   = (const float*)d_in[3];
  const float* bq   = (const float*)d_in[4];
  const float* wk   = (const float*)d_in[5];
  const float* bk   = (const float*)d_in[6];
  const float* wv   = (const float*)d_in[7];
  const float* bv   = (const float*)d_in[8];
  const float* wo   = (const float*)d_in[9];
  const float* bo   = (const float*)d_in[10];
  const float* ln1g = (const float*)d_in[11];
  const float* ln1b = (const float*)d_in[12];
  const float* ln2g = (const float*)d_in[13];
  const float* ln2b = (const float*)d_in[14];
  const float* w1   = (const float*)d_in[15];
  const float* b1   = (const float*)d_in[16];
  const float* w2   = (const float*)d_in[17];
  const float* b2   = (const float*)d_in[18];
  float* out = (float*)d_out;
  char* ws = (char*)d_ws;

  __bf16* xn    = (__bf16*)(ws + OFF_XN);
  __bf16* wqkvt = (__bf16*)(ws + OFF_WT);
  __bf16* wot   = (__bf16*)(ws + OFF_WO);
  __bf16* w1t   = (__bf16*)(ws + OFF_W1);
  __bf16* w2t   = (__bf16*)(ws + OFF_W2);
  float*  bqkv  = (float*)(ws + OFF_BQ);
  __bf16* qkv   = (__bf16*)(ws + OFF_QKV);
  __bf16* qr    = (__bf16*)(ws + OFF_QR);
  __bf16* kr    = (__bf16*)(ws + OFF_KR);
  __bf16* vt    = (__bf16*)(ws + OFF_VT);
  __bf16* attn  = (__bf16*)(ws + OFF_AO);
  float*  y     = (float*)(ws + OFF_Y);
  unsigned long long* bm = (unsigned long long*)(ws + OFF_Y);        // dead before y written
  float2* ctab  = (float2*)(ws + OFF_Y + 2097152);                   // dead before y written
  __bf16* hn    = xn;   // LN2 out (xn dead after QKV gemm)
  __bf16* h2    = qkv;  // FFN intermediate (qkv dead after vtrans)

  dim3 b256(256);
  dim3 b512(512);
  // 1: merged prologue (weight prep + bitmask + LN1 + rope table)
  prep_bm_ln<<<12038, b256, 0, stream>>>(wq, wk, wv, wo, w1, w2, bq, bk, bv,
                                         wqkvt, wot, w1t, w2t, bqkv,
                                         mask, bm, x, ln1g, ln1b, xn, pos, ctab);
  // 2-3: QKV gemm with fused rope (writes qr/kr + qkv V-slice) -> V transpose
  gemm_qkv<<<dim3(12, 64), b256, 0, stream>>>(xn, wqkvt, bqkv, qkv, qr, kr, ctab);
  vtrans<<<1024, b256, 0, stream>>>(qkv, vt);
  // 4: attention (R8 body; 1D grid for XCD swizzle)
  flash_attn<<<512, b512, 0, stream>>>(qr, kr, vt, bm, attn);
  // 5-8: out proj + residual -> y ; LN2 ; FFN (GEMMs XCD-swizzled)
  gemm_bt64<0, 0, 1><<<dim3(8, 64), b256, 0, stream>>>(attn, wot, bo, x, y, 8192, 512, 512);
  ln_fwd<<<2048, b256, 0, stream>>>(y, ln2g, ln2b, hn);
  gemm_bt<1, 1, 0><<<dim3(16, 64), b256, 0, stream>>>(hn, w1t, b1, nullptr, h2, 8192, 2048, 512);
  gemm_bt64<0, 0, 1><<<dim3(8, 64), b256, 0, stream>>>(h2, w2t, b2, y, out, 8192, 512, 2048);
}

// Round 12
// 332.655 us; speedup vs baseline: 1.0158x; 1.0158x over previous
//
#include <hip/hip_runtime.h>
#include <hip/hip_bf16.h>
#include <math.h>

typedef __attribute__((ext_vector_type(8))) __bf16 bf16x8;
typedef __attribute__((ext_vector_type(4))) __bf16 bf16x4;
typedef __attribute__((ext_vector_type(4))) float f32x4;

#define B_ 4
#define N_ 2048
#define D_ 512
#define H_ 8
#define DK_ 64
#define F_ 2048

__device__ __forceinline__ void async16(const __bf16* g, __bf16* l) {
  __builtin_amdgcn_global_load_lds((const __attribute__((address_space(1))) void*)g,
                                   (__attribute__((address_space(3))) void*)l, 16, 0, 0);
}

// ---------------- merged prologue: weight prep + bitmask + LN1 in ONE launch ----------------
__global__ __launch_bounds__(256) void prep_bm_ln(const float* __restrict__ wq,
                                                  const float* __restrict__ wk,
                                                  const float* __restrict__ wv,
                                                  const float* __restrict__ wo,
                                                  const float* __restrict__ w1,
                                                  const float* __restrict__ w2,
                                                  const float* __restrict__ bq,
                                                  const float* __restrict__ bk,
                                                  const float* __restrict__ bv,
                                                  __bf16* __restrict__ wqkvt,
                                                  __bf16* __restrict__ wot,
                                                  __bf16* __restrict__ w1t,
                                                  __bf16* __restrict__ w2t,
                                                  float* __restrict__ bqkv,
                                                  const int* __restrict__ mask,
                                                  unsigned long long* __restrict__ bm,
                                                  const float* __restrict__ x,
                                                  const float* __restrict__ g,
                                                  const float* __restrict__ bb_,
                                                  __bf16* __restrict__ xnout) {
  __shared__ float t[64][65];
  const int id = blockIdx.x;
  if (id < 774) {
    if (id >= 768) {  // bias concat (6 blocks)
      int i = (id - 768) * 256 + threadIdx.x;
      bqkv[i] = (i < 512) ? bq[i] : (i < 1024) ? bk[i - 512] : bv[i - 1024];
      return;
    }
    const float* in;
    __bf16* outp;
    int k0, n0, K, Nc;
    if (id < 256) {
      const float* src[4] = {wq, wk, wv, wo};
      __bf16* dst[4] = {wqkvt, wqkvt + 512 * 512, wqkvt + 1024 * 512, wot};
      int w = id >> 6, tl = id & 63;
      in = src[w]; outp = dst[w]; k0 = (tl & 7) * 64; n0 = (tl >> 3) * 64; K = 512; Nc = 512;
    } else if (id < 512) {
      int tl = id - 256;
      in = w1; outp = w1t; k0 = (tl & 7) * 64; n0 = (tl >> 3) * 64; K = 512; Nc = 2048;
    } else {
      int tl = id - 512;
      in = w2; outp = w2t; k0 = (tl & 31) * 64; n0 = (tl >> 5) * 64; K = 2048; Nc = 512;
    }
    const int c = threadIdx.x & 63, r4 = threadIdx.x >> 6;
#pragma unroll
    for (int p = 0; p < 16; p++) {
      int rr = p * 4 + r4;
      t[rr][c] = in[(size_t)(k0 + rr) * Nc + n0 + c];
    }
    __syncthreads();
#pragma unroll
    for (int p = 0; p < 16; p++) {
      int rr = p * 4 + r4;
      outp[(size_t)(n0 + rr) * K + k0 + c] = (__bf16)t[c][rr];
    }
  } else if (id < 774 + 8192) {
    const int bb = id - 774;
#pragma unroll
    for (int it = 0; it < 8; it++) {
      size_t tt = ((size_t)(it * 8192 + bb)) * 256 + threadIdx.x;
      int m = mask[tt];
      unsigned long long w = __ballot(m != 0);
      if ((threadIdx.x & 63) == 0) bm[tt >> 6] = w;
    }
  } else {
    int row = (id - 8966) * 4 + (threadIdx.x >> 6);
    int lane = threadIdx.x & 63;
    const float* xr = x + (size_t)row * D_ + lane * 8;
    float4 a0 = *(const float4*)xr;
    float4 a1 = *(const float4*)(xr + 4);
    float v[8] = {a0.x, a0.y, a0.z, a0.w, a1.x, a1.y, a1.z, a1.w};
    float s = 0.f;
#pragma unroll
    for (int i = 0; i < 8; i++) s += v[i];
#pragma unroll
    for (int off = 1; off < 64; off <<= 1) s += __shfl_xor(s, off);
    float mu = s * (1.f / D_);
    float q = 0.f;
#pragma unroll
    for (int i = 0; i < 8; i++) { float d = v[i] - mu; q += d * d; }
#pragma unroll
    for (int off = 1; off < 64; off <<= 1) q += __shfl_xor(q, off);
    float rs = rsqrtf(q * (1.f / D_) + 1e-5f);
    const float* gp = g + lane * 8;
    const float* bp = bb_ + lane * 8;
    alignas(16) __bf16 o[8];
#pragma unroll
    for (int i = 0; i < 8; i++) o[i] = (__bf16)((v[i] - mu) * rs * gp[i] + bp[i]);
    *(bf16x8*)(xnout + (size_t)row * D_ + lane * 8) = *(bf16x8*)o;
  }
}

// ---------------- layernorm: one wave per row of 512, fp32 in -> bf16 out (LN2) ----------------
__global__ __launch_bounds__(256) void ln_fwd(const float* __restrict__ x,
                                              const float* __restrict__ g,
                                              const float* __restrict__ b,
                                              __bf16* __restrict__ out) {
  int row = blockIdx.x * 4 + (threadIdx.x >> 6);
  int lane = threadIdx.x & 63;
  const float* xr = x + (size_t)row * D_ + lane * 8;
  float4 a0 = *(const float4*)xr;
  float4 a1 = *(const float4*)(xr + 4);
  float v[8] = {a0.x, a0.y, a0.z, a0.w, a1.x, a1.y, a1.z, a1.w};
  float s = 0.f;
#pragma unroll
  for (int i = 0; i < 8; i++) s += v[i];
#pragma unroll
  for (int off = 1; off < 64; off <<= 1) s += __shfl_xor(s, off);
  float mu = s * (1.f / D_);
  float q = 0.f;
#pragma unroll
  for (int i = 0; i < 8; i++) { float d = v[i] - mu; q += d * d; }
#pragma unroll
  for (int off = 1; off < 64; off <<= 1) q += __shfl_xor(q, off);
  float rs = rsqrtf(q * (1.f / D_) + 1e-5f);
  const float* gp = g + lane * 8;
  const float* bp = b + lane * 8;
  alignas(16) __bf16 o[8];
#pragma unroll
  for (int i = 0; i < 8; i++) o[i] = (__bf16)((v[i] - mu) * rs * gp[i] + bp[i]);
  *(bf16x8*)(out + (size_t)row * D_ + lane * 8) = *(bf16x8*)o;
}

// ---------------- fused RoPE + V transpose (one launch) ----------------
// Q is stored pre-scaled by 0.125*log2(e); flash_attn issues raw v_exp_f32 (2^x).
// R4 lesson: OCML exp2f is the precise path -- never call it (R8 validated raw asm).
// R11 lesson: fusing rope into the QKV-gemm epilogue is sub-noise-neutral (traffic
// win cancelled by epilogue table-loads/FMAs) -- keep the standalone kernel.
__global__ __launch_bounds__(256) void rope_vtrans(const __bf16* __restrict__ qkv,
                                                   const int* __restrict__ pos,
                                                   __bf16* __restrict__ qo,
                                                   __bf16* __restrict__ ko,
                                                   __bf16* __restrict__ vt) {
  __shared__ __bf16 tl[64][65];
  const int id = blockIdx.x;
  if (id < 8192) {
    int t = id * 256 + threadIdx.x;
    int d = t & 31;
    int h = (t >> 5) & 7;
    int n = (t >> 8) & (N_ - 1);
    int b = t >> 19;
    const __bf16* base = qkv + (size_t)(b * N_ + n) * 1536 + h * 64 + d;
    float q1 = (float)base[0], q2 = (float)base[32];
    float k1 = (float)base[512], k2 = (float)base[544];
    float p = (float)pos[b * N_ + n];
    float inv = __expf(-(float)d * (9.210340371976184f / 32.f));  // 10000^(-d/32)
    float ang = p * inv;
    float sn, cs;
    sincosf(ang, &sn, &cs);
    const float SC = 0.18033688011112042f;  // 0.125 * log2(e)
    size_t ob = ((size_t)(b * H_ + h) * N_ + n) * DK_ + d;
    qo[ob]      = (__bf16)((q1 * cs - q2 * sn) * SC);
    qo[ob + 32] = (__bf16)((q2 * cs + q1 * sn) * SC);
    ko[ob]      = (__bf16)(k1 * cs - k2 * sn);
    ko[ob + 32] = (__bf16)(k2 * cs + k1 * sn);
  } else {
    const int lin = id - 8192;
    const int n0 = (lin & 31) * 64, h = (lin >> 5) & 7, b = lin >> 8;
    const int c = threadIdx.x & 63, rr = threadIdx.x >> 6;
#pragma unroll
    for (int p = 0; p < 16; p++) {
      int i = p * 4 + rr;
      tl[i][c] = qkv[(size_t)(b * N_ + n0 + i) * 1536 + 1024 + h * 64 + c];
    }
    __syncthreads();
    size_t ob = (size_t)(b * H_ + h) * DK_ * N_;
#pragma unroll
    for (int p = 0; p < 16; p++) {
      int dd = p * 4 + rr;
      vt[ob + (size_t)dd * N_ + n0 + c] = tl[c][dd];
    }
  }
}

// XCD-aware block remap for GEMMs (T1; R10: -11us wall). Requires nwg % 8 == 0.
__device__ __forceinline__ int xcd_remap(int bid, int nwg) {
  return (bid & 7) * (nwg >> 3) + (bid >> 3);
}

// ---------------- GEMM 128x128, DOUBLE-BUFFERED K-loop (+ XCD swizzle) ----------------
// R7 lesson: 3-buffer counted-vmcnt regressed here (LDS 48KB dropped FFN1 4->3
// blocks/CU; TLP at 3-4 blocks/CU already hides the drain). Keep 2-buffer.
template <int RELU, int OBF, int RES>
__global__ __launch_bounds__(256) void gemm_bt(const __bf16* __restrict__ A,
                                               const __bf16* __restrict__ Bt,
                                               const float* __restrict__ bias,
                                               const float* __restrict__ res,
                                               void* __restrict__ Cout,
                                               int M, int N, int K) {
  __shared__ __bf16 As[2][128 * 32];
  __shared__ __bf16 Bs[2][128 * 32];
  const int tid = threadIdx.x;
  const int lane = tid & 63;
  const int wave = tid >> 6;
  const int quad = lane >> 4;
  const int l16 = lane & 15;
  const int nwgx = gridDim.x;
  const int gl = xcd_remap(blockIdx.y * nwgx + blockIdx.x, nwgx * gridDim.y);
  const int m0 = (gl / nwgx) * 128;
  const int n0 = (gl % nwgx) * 128;
  const int wm = (wave >> 1) * 64;
  const int wn = (wave & 1) * 64;
  f32x4 acc[4][4] = {};

  const int c0 = tid, c1 = tid + 256;
  const int ar0 = c0 >> 2, ak0 = (c0 & 3) * 8;
  const int ar1 = c1 >> 2, ak1 = (c1 & 3) * 8;

  auto stage = [&](int k0, int buf) {
    async16(A + (size_t)(m0 + ar0) * K + k0 + ak0, As[buf] + c0 * 8);
    async16(A + (size_t)(m0 + ar1) * K + k0 + ak1, As[buf] + c1 * 8);
    async16(Bt + (size_t)(n0 + ar0) * K + k0 + ak0, Bs[buf] + c0 * 8);
    async16(Bt + (size_t)(n0 + ar1) * K + k0 + ak1, Bs[buf] + c1 * 8);
  };

  stage(0, 0);
  __syncthreads();
  const int niter = K >> 5;
  for (int it = 0; it < niter; it++) {
    const int buf = it & 1;
    if (it + 1 < niter) stage((it + 1) * 32, buf ^ 1);
    bf16x8 af[4], bf[4];
#pragma unroll
    for (int mi = 0; mi < 4; mi++)
      af[mi] = *(const bf16x8*)(As[buf] + (wm + mi * 16 + l16) * 32 + quad * 8);
#pragma unroll
    for (int ni = 0; ni < 4; ni++)
      bf[ni] = *(const bf16x8*)(Bs[buf] + (wn + ni * 16 + l16) * 32 + quad * 8);
#pragma unroll
    for (int mi = 0; mi < 4; mi++)
#pragma unroll
      for (int ni = 0; ni < 4; ni++)
        acc[mi][ni] = __builtin_amdgcn_mfma_f32_16x16x32_bf16(af[mi], bf[ni], acc[mi][ni], 0, 0, 0);
    __syncthreads();  // drains stage(it+1); guards buf reuse
  }
#pragma unroll
  for (int ni = 0; ni < 4; ni++) {
    const int col = n0 + wn + ni * 16 + l16;
    const float bv = bias[col];
#pragma unroll
    for (int mi = 0; mi < 4; mi++) {
#pragma unroll
      for (int r = 0; r < 4; r++) {
        const int row = m0 + wm + mi * 16 + quad * 4 + r;
        float v = acc[mi][ni][r] + bv;
        if (RES) v += res[(size_t)row * N + col];
        if (RELU) v = fmaxf(v, 0.f);
        if (OBF) ((__bf16*)Cout)[(size_t)row * N + col] = (__bf16)v;
        else     ((float*)Cout)[(size_t)row * N + col] = v;
      }
    }
  }
}

// ---------------- GEMM 128x64, DOUBLE-BUFFERED K-loop (R8 body + XCD swizzle) ----------------
// R9 lesson: 8-wave/512-thr variant was neutral -- gemm_bt64 is not wave-starved.
template <int RELU, int OBF, int RES>
__global__ __launch_bounds__(256) void gemm_bt64(const __bf16* __restrict__ A,
                                                 const __bf16* __restrict__ Bt,
                                                 const float* __restrict__ bias,
                                                 const float* __restrict__ res,
                                                 void* __restrict__ Cout,
                                                 int M, int N, int K) {
  __shared__ __bf16 As[2][128 * 32];
  __shared__ __bf16 Bs[2][64 * 32];
  const int tid = threadIdx.x;
  const int lane = tid & 63;
  const int wave = tid >> 6;
  const int quad = lane >> 4;
  const int l16 = lane & 15;
  const int nwgx = gridDim.x;
  const int gl = xcd_remap(blockIdx.y * nwgx + blockIdx.x, nwgx * gridDim.y);
  const int m0 = (gl / nwgx) * 128;
  const int n0 = (gl % nwgx) * 64;
  const int wm = wave * 32;
  f32x4 acc[2][4] = {};

  const int ar0 = tid >> 2, ak0 = (tid & 3) * 8;

  auto stage = [&](int k0, int buf) {
    async16(A + (size_t)(m0 + ar0) * K + k0 + ak0, As[buf] + tid * 8);
    async16(A + (size_t)(m0 + 64 + ar0) * K + k0 + ak0, As[buf] + (tid + 256) * 8);
    async16(Bt + (size_t)(n0 + ar0) * K + k0 + ak0, Bs[buf] + tid * 8);
  };

  stage(0, 0);
  __syncthreads();
  const int niter = K >> 5;
  for (int it = 0; it < niter; it++) {
    const int buf = it & 1;
    if (it + 1 < niter) stage((it + 1) * 32, buf ^ 1);
    bf16x8 af[2], bf[4];
#pragma unroll
    for (int mi = 0; mi < 2; mi++)
      af[mi] = *(const bf16x8*)(As[buf] + (wm + mi * 16 + l16) * 32 + quad * 8);
#pragma unroll
    for (int ni = 0; ni < 4; ni++)
      bf[ni] = *(const bf16x8*)(Bs[buf] + (ni * 16 + l16) * 32 + quad * 8);
#pragma unroll
    for (int mi = 0; mi < 2; mi++)
#pragma unroll
      for (int ni = 0; ni < 4; ni++)
        acc[mi][ni] = __builtin_amdgcn_mfma_f32_16x16x32_bf16(af[mi], bf[ni], acc[mi][ni], 0, 0, 0);
    __syncthreads();  // drains stage(it+1); guards buf reuse
  }
#pragma unroll
  for (int ni = 0; ni < 4; ni++) {
    const int col = n0 + ni * 16 + l16;
    const float bv = bias[col];
#pragma unroll
    for (int mi = 0; mi < 2; mi++) {
#pragma unroll
      for (int r = 0; r < 4; r++) {
        const int row = m0 + wm + mi * 16 + quad * 4 + r;
        float v = acc[mi][ni][r] + bv;
        if (RES) v += res[(size_t)row * N + col];
        if (RELU) v = fmaxf(v, 0.f);
        if (OBF) ((__bf16*)Cout)[(size_t)row * N + col] = (__bf16)v;
        else     ((float*)Cout)[(size_t)row * N + col] = v;
      }
    }
  }
}

// ---------------- flash attention: 3-buffer counted-vmcnt pipeline (R8 body, ~64us) ----------------
// Pinned at ~64us by serial-chain latency (VALU cuts land in stall shadow -- R2/R8).
// Invariants: stage->consume distance >= 2 bodies (R6); counted vmcnt(3) not drain-0
// (R5, +8.5%); XCD swizzle (R4, FETCH 70.7->14.4MB); raw v_exp + rope prescale (R8).
__global__ __launch_bounds__(512, 4) void flash_attn(const __bf16* __restrict__ q,
                                                     const __bf16* __restrict__ k,
                                                     const __bf16* __restrict__ vt,
                                                     const unsigned long long* __restrict__ bm,
                                                     __bf16* __restrict__ out) {
  const int bid = blockIdx.x;
  const int gl = ((bid & 7) << 6) | (bid >> 3);  // bijective: 512 = 8*64
  const int qt = gl & 15;
  const int h = (gl >> 4) & 7;
  const int b = gl >> 7;
  const int tid = threadIdx.x;
  const int lane = tid & 63, wave = tid >> 6;   // wave 0..7
  const int quad = lane >> 4, l16 = lane & 15;
  __shared__ __bf16 Ks[3][64 * 64];
  __shared__ __bf16 Vs[3][64 * 64];
  __shared__ __bf16 P[8][16 * 68];  // [wave][qrow x keys(stride 68)]
  const size_t bh = (size_t)b * H_ + h;
  const __bf16* qp = q + (bh * N_ + qt * 128 + wave * 16) * DK_;
  bf16x8 qf[2];
#pragma unroll
  for (int ks = 0; ks < 2; ks++)
    qf[ks] = *(const bf16x8*)(qp + l16 * DK_ + ks * 32 + quad * 8);  // pre-scaled at rope
  const __bf16* kbase = k + bh * N_ * DK_;
  const __bf16* vbase = vt + bh * DK_ * N_;
  const int qrow0 = qt * 128 + wave * 16 + l16;
  const unsigned long long* bmr = bm + (size_t)(b * N_ + qrow0) * (N_ / 64);
  const int xo = l16 & 7;  // read-side XOR (== row&7 for all fragment rows)

  f32x4 oacc[4] = {};
  float lsum = 0.f;

  const int sr = tid >> 3;
  const int sj = (tid & 7) ^ (sr & 7);
  const __bf16* ksrc = kbase + sr * DK_ + sj * 8;
  const __bf16* vsrc = vbase + (size_t)sr * N_ + sj * 8;

  auto stage = [&](int kt, int buf) {
    async16(ksrc + (size_t)kt * 64 * DK_, Ks[buf] + tid * 8);
    async16(vsrc + kt * 64, Vs[buf] + tid * 8);
  };

  // prologue: stage tiles 0 and 1; wait only for tile 0 (tile 1 + mask stay in flight)
  stage(0, 0);
  stage(1, 1);
  unsigned long long mw = bmr[0];
  asm volatile("s_waitcnt vmcnt(3)" ::: "memory");
  __builtin_amdgcn_s_barrier();
  __builtin_amdgcn_sched_barrier(0);

  for (int kt = 0; kt < 32; kt++) {
    const int buf = kt % 3;
    // uniform vmem cluster: 2 stage loads + 1 mask load per iteration (dummy at tail)
    const int nstage = (kt + 2 < 32) ? kt + 2 : 31;
    stage(nstage, (kt + 2) % 3);
    const int nmask = (kt + 1 < 32) ? kt + 1 : 31;
    const unsigned long long mw_nxt = bmr[nmask];

    const unsigned long long mws = mw >> (quad * 4);
    // S^T tile: A-operand = K fragment, B-operand = Q fragment (col = qrow)
#pragma unroll
    for (int ci = 0; ci < 4; ci++) {
      const int row = ci * 16 + l16;
      bf16x8 kf0 = *(const bf16x8*)(Ks[buf] + (row * 8 + (quad ^ xo)) * 8);
      bf16x8 kf1 = *(const bf16x8*)(Ks[buf] + (row * 8 + ((4 + quad) ^ xo)) * 8);
      f32x4 a = {0.f, 0.f, 0.f, 0.f};
      a = __builtin_amdgcn_mfma_f32_16x16x32_bf16(kf0, qf[0], a, 0, 0, 0);
      a = __builtin_amdgcn_mfma_f32_16x16x32_bf16(kf1, qf[1], a, 0, 0, 0);
      const unsigned int nib = (unsigned int)(mws >> (ci * 16)) & 15u;
      bf16x4 pk;
#pragma unroll
      for (int r4 = 0; r4 < 4; r4++) {
        float in = ((nib >> r4) & 1u) ? a[r4] : -1e30f;
        float p;
        asm("v_exp_f32 %0, %1" : "=v"(p) : "v"(in));  // 2^in; S pre-scaled by log2e
        lsum += p;
        pk[r4] = (__bf16)p;
      }
      *(bf16x4*)(&P[wave][0] + l16 * 68 + ci * 16 + quad * 4) = pk;
    }
    // P^T fragments (B-operand): row l16 = qrow, keys quad*8+j (same-wave write->read)
    bf16x8 pf0 = *(const bf16x8*)(&P[wave][0] + l16 * 68 + quad * 8);
    bf16x8 pf1 = *(const bf16x8*)(&P[wave][0] + l16 * 68 + 32 + quad * 8);
    // out^T += V^T . P^T
#pragma unroll
    for (int ni = 0; ni < 4; ni++) {
      const int row = ni * 16 + l16;
      bf16x8 vf0 = *(const bf16x8*)(Vs[buf] + (row * 8 + (quad ^ xo)) * 8);
      bf16x8 vf1 = *(const bf16x8*)(Vs[buf] + (row * 8 + ((4 + quad) ^ xo)) * 8);
      oacc[ni] = __builtin_amdgcn_mfma_f32_16x16x32_bf16(vf0, pf0, oacc[ni], 0, 0, 0);
      oacc[ni] = __builtin_amdgcn_mfma_f32_16x16x32_bf16(vf1, pf1, oacc[ni], 0, 0, 0);
    }
    // counted wait: previous stage (issued last iter) retired; this iter's
    // 2 stage loads + 1 mask load may remain in flight across the barrier.
    asm volatile("s_waitcnt vmcnt(3)" ::: "memory");
    __builtin_amdgcn_s_barrier();
    __builtin_amdgcn_sched_barrier(0);
    mw = mw_nxt;
  }
  // row-sum: combine the 4 quads; then store out^T (col l16 = qrow) as 8B packed
  lsum += __shfl_xor(lsum, 16);
  lsum += __shfl_xor(lsum, 32);
  const float inv_l = (lsum > 0.f) ? 1.f / lsum : 0.f;
#pragma unroll
  for (int ni = 0; ni < 4; ni++) {
    bf16x4 ov;
#pragma unroll
    for (int r = 0; r < 4; r++) ov[r] = (__bf16)(oacc[ni][r] * inv_l);
    *(bf16x4*)(out + ((size_t)b * N_ + qrow0) * D_ + h * DK_ + ni * 16 + quad * 4) = ov;
  }
}

// ---------------- workspace layout (bytes) ----------------
static constexpr size_t OFF_XN  = 0;                         // 8,388,608 (xn; reused as LN2 out)
static constexpr size_t OFF_WT  = 8388608;                   // 1,572,864
static constexpr size_t OFF_WO  = OFF_WT + 1572864;          // 524,288
static constexpr size_t OFF_W1  = OFF_WO + 524288;           // 2,097,152
static constexpr size_t OFF_W2  = OFF_W1 + 2097152;          // 2,097,152
static constexpr size_t OFF_BQ  = OFF_W2 + 2097152;          // 6,144
static constexpr size_t OFF_QKV = OFF_BQ + 6144;             // 25,165,824 (h2 overlay)
static constexpr size_t OFF_QR  = OFF_QKV + 25165824;        // 8,388,608
static constexpr size_t OFF_KR  = OFF_QR + 8388608;          // 8,388,608
static constexpr size_t OFF_VT  = OFF_KR + 8388608;          // 8,388,608
static constexpr size_t OFF_AO  = OFF_VT + 8388608;          // 8,388,608
static constexpr size_t OFF_Y   = OFF_AO + 8388608;          // 16,777,216 fp32 y (bm overlays pre-y)
// total = 90,183,680 bytes

extern "C" void kernel_launch(void* const* d_in, const int* in_sizes, int n_in,
                              void* d_out, int out_size, void* d_ws, size_t ws_size,
                              hipStream_t stream) {
  const float* x    = (const float*)d_in[0];
  const int*   mask = (const int*)d_in[1];
  const int*   pos  = (const int*)d_in[2];
  const float* wq   = (const float*)d_in[3];
  const float* bq   = (const float*)d_in[4];
  const float* wk   = (const float*)d_in[5];
  const float* bk   = (const float*)d_in[6];
  const float* wv   = (const float*)d_in[7];
  const float* bv   = (const float*)d_in[8];
  const float* wo   = (const float*)d_in[9];
  const float* bo   = (const float*)d_in[10];
  const float* ln1g = (const float*)d_in[11];
  const float* ln1b = (const float*)d_in[12];
  const float* ln2g = (const float*)d_in[13];
  const float* ln2b = (const float*)d_in[14];
  const float* w1   = (const float*)d_in[15];
  const float* b1   = (const float*)d_in[16];
  const float* w2   = (const float*)d_in[17];
  const float* b2   = (const float*)d_in[18];
  float* out = (float*)d_out;
  char* ws = (char*)d_ws;

  __bf16* xn    = (__bf16*)(ws + OFF_XN);
  __bf16* wqkvt = (__bf16*)(ws + OFF_WT);
  __bf16* wot   = (__bf16*)(ws + OFF_WO);
  __bf16* w1t   = (__bf16*)(ws + OFF_W1);
  __bf16* w2t   = (__bf16*)(ws + OFF_W2);
  float*  bqkv  = (float*)(ws + OFF_BQ);
  __bf16* qkv   = (__bf16*)(ws + OFF_QKV);
  __bf16* qr    = (__bf16*)(ws + OFF_QR);
  __bf16* kr    = (__bf16*)(ws + OFF_KR);
  __bf16* vt    = (__bf16*)(ws + OFF_VT);
  __bf16* attn  = (__bf16*)(ws + OFF_AO);
  float*  y     = (float*)(ws + OFF_Y);
  unsigned long long* bm = (unsigned long long*)(ws + OFF_Y);  // dead before y written
  __bf16* hn    = xn;   // LN2 out (xn dead after QKV gemm)
  __bf16* h2    = qkv;  // FFN intermediate (qkv dead after rope/v_trans)

  dim3 b256(256);
  dim3 b512(512);
  // 1: merged prologue (weight prep + bitmask + LN1)
  prep_bm_ln<<<11014, b256, 0, stream>>>(wq, wk, wv, wo, w1, w2, bq, bk, bv,
                                         wqkvt, wot, w1t, w2t, bqkv,
                                         mask, bm, x, ln1g, ln1b, xn);
  // 2-3: QKV gemm -> fused rope + v transpose
  gemm_bt<0, 1, 0><<<dim3(12, 64), b256, 0, stream>>>(xn, wqkvt, bqkv, nullptr, qkv, 8192, 1536, 512);
  rope_vtrans<<<9216, b256, 0, stream>>>(qkv, pos, qr, kr, vt);
  // 4: attention (R8 body; 1D grid for XCD swizzle)
  flash_attn<<<512, b512, 0, stream>>>(qr, kr, vt, bm, attn);
  // 5-8: out proj + residual -> y ; LN2 ; FFN (GEMMs XCD-swizzled)
  gemm_bt64<0, 0, 1><<<dim3(8, 64), b256, 0, stream>>>(attn, wot, bo, x, y, 8192, 512, 512);
  ln_fwd<<<2048, b256, 0, stream>>>(y, ln2g, ln2b, hn);
  gemm_bt<1, 1, 0><<<dim3(16, 64), b256, 0, stream>>>(hn, w1t, b1, nullptr, h2, 8192, 2048, 512);
  gemm_bt64<0, 0, 1><<<dim3(8, 64), b256, 0, stream>>>(h2, w2t, b2, y, out, 8192, 512, 2048);
}